// Round 6
// baseline (116.286 us; speedup 1.0000x reference)
//
#include <hip/hip_runtime.h>
#include <hip/hip_bf16.h>

typedef __attribute__((ext_vector_type(8))) short short8;
typedef __attribute__((ext_vector_type(4))) float f32x4;

__device__ __forceinline__ unsigned short f2bf(float f){
    union { float f; unsigned u; } uf; uf.f = f;
    unsigned u = uf.u;
    u += 0x7FFFu + ((u >> 16) & 1u);   // RNE
    return (unsigned short)(u >> 16);
}
__device__ __forceinline__ int pack2(float a, float b){
    return (int)((unsigned)f2bf(a) | ((unsigned)f2bf(b) << 16));
}
__device__ __forceinline__ unsigned cvtpk(float lo, float hi){
    unsigned r;
    asm("v_cvt_pk_bf16_f32 %0, %1, %2" : "=v"(r) : "v"(lo), "v"(hi));
    return r;
}
__device__ __forceinline__ f32x4 vmax4(f32x4 a, f32x4 b){
    f32x4 r; r[0]=fmaxf(a[0],b[0]); r[1]=fmaxf(a[1],b[1]);
    r[2]=fmaxf(a[2],b[2]); r[3]=fmaxf(a[3],b[3]); return r;
}

#define N_SPATIAL 1600
#define ATTN_SCALE 0.17677669529663687f  /* 32^-0.5 */
#define PADW 132   /* dwords per x_lds row = 264 u16 (256 c + 8 pad) */

// ---------------- K1 fused: blocks [0,800) qkv GEMM ; [800,7200) pev ----------------
__global__ __launch_bounds__(256) void k_fuse1(const float* __restrict__ x,
                                               const float* __restrict__ wq,
                                               const float* __restrict__ qg,
                                               const float* __restrict__ qb,
                                               const float* __restrict__ qm,
                                               const float* __restrict__ qv,
                                               const float* __restrict__ pw,
                                               const float* __restrict__ pg,
                                               const float* __restrict__ pb,
                                               const float* __restrict__ pm,
                                               const float* __restrict__ pv,
                                               unsigned short* __restrict__ vbuf,
                                               unsigned short* __restrict__ qk_t){
    __shared__ unsigned int x_lds[64*PADW];   // 33792 B
    int bi = blockIdx.x;
    int tid = threadIdx.x;
    if (bi < 800){
        // ---- qkv: out tile 64n x 64o ; A = x^T (LDS), B = W (global) ----
        int b = bi/200, ot = (bi/25)%8, nt = bi%25;
        int o0 = ot*64, n0 = nt*64;
        int w = tid>>6, lane = tid&63, ql = lane&15, lg = lane>>4;

        // stage x[b][0..255][n0..n0+63] -> x_lds[n][c] (bf16, padded rows)
        int c2 = (tid & 127)*2, nh = (tid>>7)*32;
        const float* s0 = x + ((size_t)(b*256 + c2))*N_SPATIAL + n0 + nh;
        const float* s1 = s0 + N_SPATIAL;
        #pragma unroll
        for (int j=0;j<32;j+=4){
            float4 a = *reinterpret_cast<const float4*>(s0 + j);
            float4 c = *reinterpret_cast<const float4*>(s1 + j);
            int base = (nh+j)*PADW + (c2>>1);
            x_lds[base         ] = (unsigned)pack2(a.x, c.x);
            x_lds[base +   PADW] = (unsigned)pack2(a.y, c.y);
            x_lds[base + 2*PADW] = (unsigned)pack2(a.z, c.z);
            x_lds[base + 3*PADW] = (unsigned)pack2(a.w, c.w);
        }
        __syncthreads();

        f32x4 acc[4];
        #pragma unroll
        for (int t=0;t<4;t++) acc[t] = (f32x4){0.f,0.f,0.f,0.f};
        const unsigned short* xl = reinterpret_cast<const unsigned short*>(x_lds);
        #pragma unroll
        for (int k0=0; k0<256; k0+=32){
            short8 af = *reinterpret_cast<const short8*>(xl + (16*w + ql)*264 + k0 + lg*8);
            #pragma unroll
            for (int t=0;t<4;t++){
                const float* wsrc = wq + (size_t)(o0 + 16*t + ql)*256 + k0 + lg*8;
                float4 f0 = *reinterpret_cast<const float4*>(wsrc);
                float4 f1 = *reinterpret_cast<const float4*>(wsrc + 4);
                union{int4 i; short8 s;} bw;
                bw.i = make_int4(pack2(f0.x,f0.y), pack2(f0.z,f0.w),
                                 pack2(f1.x,f1.y), pack2(f1.z,f1.w));
                acc[t] = __builtin_amdgcn_mfma_f32_16x16x32_bf16(af, bw.s, acc[t], 0,0,0);
            }
        }
        #pragma unroll
        for (int t=0;t<4;t++){
            int o = o0 + 16*t + ql;
            float inv = qg[o] * rsqrtf(qv[o] + 1e-5f);
            float b2  = qb[o] - qm[o]*inv;
            int grp = o >> 5, d = o & 31;
            unsigned short* dst = qk_t + ((size_t)(b*16 + grp)*N_SPATIAL)*32 + d;
            #pragma unroll
            for (int r=0;r<4;r++){
                int n = n0 + 16*w + lg*4 + r;
                float z = acc[t][r]*inv + b2;
                float y = z / (1.f + __expf(-z));
                dst[(size_t)n*32] = f2bf(y);
            }
        }
    } else {
        // ---- pev: v = x + BN(dwconv3x3(x)), bf16 (B,C,N) ----
        int idx = (bi-800)*256 + tid;          // < 4*256*1600
        int n  = idx % N_SPATIAL;
        int bc = idx / N_SPATIAL;
        int c  = bc & 255;
        int h = n / 40, w2 = n % 40;
        const float* xp = x + (size_t)bc*N_SPATIAL;
        float acc = 0.f;
        #pragma unroll
        for (int kh=-1; kh<=1; kh++){
            int hh = h + kh; if ((unsigned)hh >= 40u) continue;
            #pragma unroll
            for (int kw=-1; kw<=1; kw++){
                int ww = w2 + kw; if ((unsigned)ww >= 40u) continue;
                acc += xp[hh*40+ww] * pw[c*9 + (kh+1)*3 + (kw+1)];
            }
        }
        float inv = pg[c] * rsqrtf(pv[c] + 1e-5f);
        float out = xp[n] + acc*inv + (pb[c] - pm[c]*inv);
        vbuf[idx] = f2bf(out);
    }
}

// ---------------- K2: flash attention, swapped-QK^T, split-K, K-prefetch ----------------
__global__ __launch_bounds__(256) void k_attn2(const unsigned short* __restrict__ qk_t,
                                               const unsigned short* __restrict__ v,
                                               unsigned short* __restrict__ ao_t,
                                               float* __restrict__ po,
                                               float* __restrict__ pmx,
                                               float* __restrict__ psm,
                                               int nsplit, int tps){
    __shared__ alignas(16) unsigned short v_lds[2][32*72];
    int bi = blockIdx.x;
    int s  = bi / 800, qb = bi - s*800;
    int b = qb/200, h = (qb/25)%8, qt = qb%25;
    int nq0 = qt*64;
    int tid = threadIdx.x, w = tid>>6, lane = tid&63;
    int ql = lane&15, lg = lane>>4;

    const unsigned short* qsrc = qk_t + ((size_t)(b*16+h)*N_SPATIAL)*32;
    const unsigned short* ksrc = qk_t + ((size_t)(b*16+8+h)*N_SPATIAL)*32;
    const unsigned short* vsrc = v + ((size_t)(b*256+h*32))*N_SPATIAL;

    short8 qf = *reinterpret_cast<const short8*>(qsrc + (size_t)(nq0 + w*16 + ql)*32 + lg*8);

    int kt0 = s*tps, kt1 = kt0+tps; if (kt1 > 25) kt1 = 25;

    int sd = tid>>3, sc8 = (tid&7)*8;
    const unsigned short* vstage = vsrc + (size_t)sd*N_SPATIAL + sc8;
    { int4 sv = *reinterpret_cast<const int4*>(vstage + kt0*64);
      *reinterpret_cast<int4*>(&v_lds[0][sd*72 + sc8]) = sv; }

    // prefetch K frags for kt0
    const unsigned short* kp = ksrc + (size_t)(kt0*64 + ql)*32 + lg*8;
    short8 ka0 = *reinterpret_cast<const short8*>(kp);
    short8 ka1 = *reinterpret_cast<const short8*>(kp + 16*32);
    short8 ka2 = *reinterpret_cast<const short8*>(kp + 32*32);
    short8 ka3 = *reinterpret_cast<const short8*>(kp + 48*32);
    __syncthreads();

    float M = -1e30f, S = 0.f;
    f32x4 o0 = (f32x4){0.f,0.f,0.f,0.f};
    f32x4 o1 = (f32x4){0.f,0.f,0.f,0.f};
    int bufp = 0;

    for (int kt = kt0; kt < kt1; ++kt){
        bool more = (kt+1 < kt1);
        short8 kb0, kb1, kb2, kb3; int4 sv;
        if (more){
            const unsigned short* kpn = ksrc + (size_t)((kt+1)*64 + ql)*32 + lg*8;
            kb0 = *reinterpret_cast<const short8*>(kpn);
            kb1 = *reinterpret_cast<const short8*>(kpn + 16*32);
            kb2 = *reinterpret_cast<const short8*>(kpn + 32*32);
            kb3 = *reinterpret_cast<const short8*>(kpn + 48*32);
            sv  = *reinterpret_cast<const int4*>(vstage + (kt+1)*64);
        }

        f32x4 z = (f32x4){0.f,0.f,0.f,0.f};
        f32x4 p0 = __builtin_amdgcn_mfma_f32_16x16x32_bf16(ka0, qf, z, 0,0,0);
        f32x4 p1 = __builtin_amdgcn_mfma_f32_16x16x32_bf16(ka1, qf, z, 0,0,0);
        f32x4 p2 = __builtin_amdgcn_mfma_f32_16x16x32_bf16(ka2, qf, z, 0,0,0);
        f32x4 p3 = __builtin_amdgcn_mfma_f32_16x16x32_bf16(ka3, qf, z, 0,0,0);

        f32x4 mm = vmax4(vmax4(p0,p1), vmax4(p2,p3));
        float mx = fmaxf(fmaxf(mm[0],mm[1]), fmaxf(mm[2],mm[3]));
        mx = fmaxf(mx, __shfl_xor(mx, 16));
        mx = fmaxf(mx, __shfl_xor(mx, 32));
        float mn = fmaxf(M, mx);
        float al = __expf(ATTN_SCALE*(M - mn));
        float nb = -ATTN_SCALE*mn;
        #pragma unroll
        for (int r=0;r<4;r++){
            p0[r] = __expf(fmaf(p0[r], ATTN_SCALE, nb));
            p1[r] = __expf(fmaf(p1[r], ATTN_SCALE, nb));
            p2[r] = __expf(fmaf(p2[r], ATTN_SCALE, nb));
            p3[r] = __expf(fmaf(p3[r], ATTN_SCALE, nb));
        }
        float ts = ((p0[0]+p0[1])+(p0[2]+p0[3])) + ((p1[0]+p1[1])+(p1[2]+p1[3]))
                 + ((p2[0]+p2[1])+(p2[2]+p2[3])) + ((p3[0]+p3[1])+(p3[2]+p3[3]));
        ts += __shfl_xor(ts, 16);
        ts += __shfl_xor(ts, 32);
        S = S*al + ts;
        M = mn;
        o0 *= al; o1 *= al;

        union { int4 i; short8 sv8; } pb0, pb1;
        pb0.i = make_int4((int)cvtpk(p0[0],p0[1]), (int)cvtpk(p0[2],p0[3]),
                          (int)cvtpk(p1[0],p1[1]), (int)cvtpk(p1[2],p1[3]));
        pb1.i = make_int4((int)cvtpk(p2[0],p2[1]), (int)cvtpk(p2[2],p2[3]),
                          (int)cvtpk(p3[0],p3[1]), (int)cvtpk(p3[2],p3[3]));

        const unsigned short* vr0 = &v_lds[bufp][(size_t)ql*72];
        const unsigned short* vr1 = &v_lds[bufp][(size_t)(16+ql)*72];
        {
            uint2 a0 = *reinterpret_cast<const uint2*>(vr0 + 4*lg);
            uint2 a1 = *reinterpret_cast<const uint2*>(vr0 + 16 + 4*lg);
            union { int4 i; short8 sv8; } vf; vf.i = make_int4((int)a0.x,(int)a0.y,(int)a1.x,(int)a1.y);
            o0 = __builtin_amdgcn_mfma_f32_16x16x32_bf16(vf.sv8, pb0.sv8, o0, 0,0,0);
            uint2 b0 = *reinterpret_cast<const uint2*>(vr0 + 32 + 4*lg);
            uint2 b1 = *reinterpret_cast<const uint2*>(vr0 + 48 + 4*lg);
            vf.i = make_int4((int)b0.x,(int)b0.y,(int)b1.x,(int)b1.y);
            o0 = __builtin_amdgcn_mfma_f32_16x16x32_bf16(vf.sv8, pb1.sv8, o0, 0,0,0);
        }
        {
            uint2 a0 = *reinterpret_cast<const uint2*>(vr1 + 4*lg);
            uint2 a1 = *reinterpret_cast<const uint2*>(vr1 + 16 + 4*lg);
            union { int4 i; short8 sv8; } vf; vf.i = make_int4((int)a0.x,(int)a0.y,(int)a1.x,(int)a1.y);
            o1 = __builtin_amdgcn_mfma_f32_16x16x32_bf16(vf.sv8, pb0.sv8, o1, 0,0,0);
            uint2 b0 = *reinterpret_cast<const uint2*>(vr1 + 32 + 4*lg);
            uint2 b1 = *reinterpret_cast<const uint2*>(vr1 + 48 + 4*lg);
            vf.i = make_int4((int)b0.x,(int)b0.y,(int)b1.x,(int)b1.y);
            o1 = __builtin_amdgcn_mfma_f32_16x16x32_bf16(vf.sv8, pb1.sv8, o1, 0,0,0);
        }

        if (more){
            *reinterpret_cast<int4*>(&v_lds[bufp^1][sd*72 + sc8]) = sv;
            __syncthreads();
            bufp ^= 1;
            ka0 = kb0; ka1 = kb1; ka2 = kb2; ka3 = kb3;
        }
    }

    if (nsplit == 1){
        float inv = 1.f / S;
        size_t rowoff = ((size_t)b*N_SPATIAL + nq0 + w*16 + ql)*256 + h*32;
        uint2 w0 = make_uint2((unsigned)pack2(o0[0]*inv, o0[1]*inv),
                              (unsigned)pack2(o0[2]*inv, o0[3]*inv));
        *reinterpret_cast<uint2*>(ao_t + rowoff + 4*lg) = w0;
        uint2 w1 = make_uint2((unsigned)pack2(o1[0]*inv, o1[1]*inv),
                              (unsigned)pack2(o1[2]*inv, o1[3]*inv));
        *reinterpret_cast<uint2*>(ao_t + rowoff + 16 + 4*lg) = w1;
    } else {
        float* op = po + ((size_t)bi*64 + w*16 + ql)*32;
        *reinterpret_cast<f32x4*>(op + 4*lg) = o0;
        *reinterpret_cast<f32x4*>(op + 16 + 4*lg) = o1;
        if (lg == 0){
            pmx[(size_t)bi*64 + w*16 + ql] = M;
            psm[(size_t)bi*64 + w*16 + ql] = S;
        }
    }
}

// ---------------- K3: combine split-K partials ----------------
__global__ __launch_bounds__(256) void k_comb(const float* __restrict__ po,
                                              const float* __restrict__ pmx,
                                              const float* __restrict__ psm,
                                              unsigned short* __restrict__ ao_t,
                                              int nsplit){
    int qb = blockIdx.x;                 // 800
    int b = qb/200, h = (qb/25)%8, qt = qb%25;
    int t = threadIdx.x;
    int q = t>>2, d0 = (t&3)*8;
    float mg = -1e30f;
    for (int s=0; s<nsplit; s++)
        mg = fmaxf(mg, pmx[((size_t)s*800 + qb)*64 + q]);
    float den = 0.f;
    float acc[8];
    #pragma unroll
    for (int j=0;j<8;j++) acc[j]=0.f;
    for (int s=0; s<nsplit; s++){
        size_t idx = ((size_t)s*800 + qb)*64 + q;
        float f = __expf(ATTN_SCALE*(pmx[idx] - mg));
        den += f * psm[idx];
        const float* op = po + idx*32 + d0;
        float4 a = *reinterpret_cast<const float4*>(op);
        float4 c = *reinterpret_cast<const float4*>(op + 4);
        acc[0] += f*a.x; acc[1] += f*a.y; acc[2] += f*a.z; acc[3] += f*a.w;
        acc[4] += f*c.x; acc[5] += f*c.y; acc[6] += f*c.z; acc[7] += f*c.w;
    }
    float inv = 1.f/den;
    int4 outw;
    outw.x = pack2(acc[0]*inv, acc[1]*inv);
    outw.y = pack2(acc[2]*inv, acc[3]*inv);
    outw.z = pack2(acc[4]*inv, acc[5]*inv);
    outw.w = pack2(acc[6]*inv, acc[7]*inv);
    *reinterpret_cast<int4*>(ao_t + ((size_t)b*N_SPATIAL + qt*64 + q)*256 + h*32 + d0) = outw;
}

// ---------------- K4: proj GEMM, zero-LDS (A=W, B=ao^T direct) ----------------
__global__ __launch_bounds__(256) void k_proj2(const unsigned short* __restrict__ ao_t,
                                               const float* __restrict__ wp,
                                               const float* __restrict__ prg,
                                               const float* __restrict__ prb,
                                               const float* __restrict__ prm,
                                               const float* __restrict__ prv,
                                               float* __restrict__ out){
    int bi = blockIdx.x;                 // 800 = 4b * 4ot * 50nt
    int b = bi/200, rem = bi%200;
    int ot = rem/50, nt = rem%50;
    int o0 = ot*64, n0 = nt*32;
    int tid = threadIdx.x, w = tid>>6, lane = tid&63;
    int ql = lane&15, lg = lane>>4;

    f32x4 acc[2];
    acc[0] = (f32x4){0.f,0.f,0.f,0.f};
    acc[1] = (f32x4){0.f,0.f,0.f,0.f};
    const float* asrc = wp + (size_t)(o0 + 16*w + ql)*256;
    const unsigned short* b0src = ao_t + ((size_t)b*N_SPATIAL + n0 + ql)*256;
    const unsigned short* b1src = b0src + 16*256;
    #pragma unroll
    for (int k0=0; k0<256; k0+=32){
        const float* wsrc = asrc + k0 + lg*8;
        float4 f0 = *reinterpret_cast<const float4*>(wsrc);
        float4 f1 = *reinterpret_cast<const float4*>(wsrc + 4);
        union{int4 i; short8 s;} aw;
        aw.i = make_int4(pack2(f0.x,f0.y), pack2(f0.z,f0.w),
                         pack2(f1.x,f1.y), pack2(f1.z,f1.w));
        short8 bf0 = *reinterpret_cast<const short8*>(b0src + k0 + lg*8);
        short8 bf1 = *reinterpret_cast<const short8*>(b1src + k0 + lg*8);
        acc[0] = __builtin_amdgcn_mfma_f32_16x16x32_bf16(aw.s, bf0, acc[0], 0,0,0);
        acc[1] = __builtin_amdgcn_mfma_f32_16x16x32_bf16(aw.s, bf1, acc[1], 0,0,0);
    }
    #pragma unroll
    for (int r=0;r<4;r++){
        int o = o0 + 16*w + lg*4 + r;
        float inv = prg[o] * rsqrtf(prv[o] + 1e-5f);
        float b2  = prb[o] - prm[o]*inv;
        float* dst = out + ((size_t)(b*256 + o))*N_SPATIAL;
        #pragma unroll
        for (int t=0;t<2;t++){
            int n = n0 + 16*t + ql;
            float z = acc[t][r]*inv + b2;
            dst[n] = z / (1.f + __expf(-z));
        }
    }
}

extern "C" void kernel_launch(void* const* d_in, const int* in_sizes, int n_in,
                              void* d_out, int out_size, void* d_ws, size_t ws_size,
                              hipStream_t stream) {
    const float* x      = (const float*)d_in[0];
    const float* qkv_w  = (const float*)d_in[1];
    const float* qkv_g  = (const float*)d_in[2];
    const float* qkv_b  = (const float*)d_in[3];
    const float* qkv_m  = (const float*)d_in[4];
    const float* qkv_v  = (const float*)d_in[5];
    const float* proj_w = (const float*)d_in[6];
    const float* proj_g = (const float*)d_in[7];
    const float* proj_b = (const float*)d_in[8];
    const float* proj_m = (const float*)d_in[9];
    const float* proj_v = (const float*)d_in[10];
    const float* pe_w   = (const float*)d_in[11];
    const float* pe_g   = (const float*)d_in[12];
    const float* pe_b   = (const float*)d_in[13];
    const float* pe_m   = (const float*)d_in[14];
    const float* pe_v   = (const float*)d_in[15];

    char* ws = (char*)d_ws;
    unsigned short* vbuf = (unsigned short*)(ws);                 // 3,276,800 B
    unsigned short* qk_t = (unsigned short*)(ws + 3276800);       // 6,553,600 B
    unsigned short* ao_t = (unsigned short*)(ws + 9830400);       // 3,276,800 B
    float* outp = (float*)d_out;

    const size_t base = 13107200;
    const size_t per_split = 800ull*64*32*4 + 2ull*800*64*4;      // 6,963,200 B
    int S = 1;
    if      (ws_size >= base + 5*per_split) S = 5;
    else if (ws_size >= base + 2*per_split) S = 2;
    float* po  = (float*)(ws + base);
    float* pmx = (float*)(ws + base + (size_t)S*800*64*32*4);
    float* psm = pmx + (size_t)S*800*64;
    int tps = (25 + S - 1)/S;

    k_fuse1<<<7200, 256, 0, stream>>>(x, qkv_w, qkv_g, qkv_b, qkv_m, qkv_v,
                                      pe_w, pe_g, pe_b, pe_m, pe_v, vbuf, qk_t);
    k_attn2<<<800*S, 256, 0, stream>>>(qk_t, vbuf, ao_t, po, pmx, psm, S, tps);
    if (S > 1)
        k_comb<<<800, 256, 0, stream>>>(po, pmx, psm, ao_t, S);
    k_proj2<<<800, 256, 0, stream>>>(ao_t, proj_w, proj_g, proj_b, proj_m, proj_v, outp);
}